// Round 6
// baseline (236.872 us; speedup 1.0000x reference)
//
#include <hip/hip_runtime.h>

#define NN 50000
#define NE 800000
#define DD 128
#define NL 3
#define ELLW 64
#define MT_TOTAL (NN / 16)   // 3125 tiles of 16 rows

typedef short bf16x8 __attribute__((ext_vector_type(8)));
typedef float f32x4 __attribute__((ext_vector_type(4)));
typedef _Float16 half8 __attribute__((ext_vector_type(8)));
typedef int i32x4 __attribute__((ext_vector_type(4)));
typedef float f32x4v __attribute__((ext_vector_type(4)));

__device__ __forceinline__ unsigned short f2bf(float x) {
  unsigned u = __float_as_uint(x);
  u += 0x7FFFu + ((u >> 16) & 1u);          // RTN-even
  return (unsigned short)(u >> 16);
}
__device__ __forceinline__ float bf2f(unsigned short h) {
  return __uint_as_float(((unsigned)h) << 16);
}
__device__ __forceinline__ void cvt8(float4 z0, float4 z1, bf16x8* hi, bf16x8* lo) {
  float zz[8] = {z0.x, z0.y, z0.z, z0.w, z1.x, z1.y, z1.z, z1.w};
#pragma unroll
  for (int i = 0; i < 8; ++i) {
    unsigned short h = f2bf(zz[i]);
    (*hi)[i] = (short)h;
    (*lo)[i] = (short)f2bf(zz[i] - bf2f(h));
  }
}

// ---------------- ELL build: one atomic per edge ----------------
__global__ __launch_bounds__(256) void build_ell_k(const int* __restrict__ ei,
                                                   int* __restrict__ cnt,
                                                   int* __restrict__ ell) {
  int e = blockIdx.x * 256 + threadIdx.x;
  if (e >= NE) return;
  int s = ei[e];        // src
  int d = ei[NE + e];   // dst
  int pos = atomicAdd(&cnt[d], 1);
  if (pos < ELLW) ell[(size_t)d * ELLW + pos] = s;
}

// ---------------- one-time W fragment pack: fp32 -> bf16 hi/lo, MFMA B-frag order ----
__global__ __launch_bounds__(256) void pack_w_k(const float* __restrict__ W1,
                                                const float* __restrict__ W2,
                                                unsigned short* __restrict__ Wp) {
  int t = blockIdx.x * 256 + threadIdx.x;
  if (t >= 6 * 2048) return;
  int m = t >> 11;
  int rem = t & 2047;              // (nt*4+ks)*64 + lane
  int l = rem & 63;
  int ntks = rem >> 6;             // 0..31
  int ks = ntks & 3, nt = ntks >> 2;
  const float* W = (m < 3) ? (W1 + (size_t)m * DD * DD) : (W2 + (size_t)(m - 3) * DD * DD);
  int col = nt * 16 + (l & 15);
  int k0 = ks * 32 + (l >> 4) * 8;
  unsigned short* hi = Wp + (size_t)m * 2 * DD * DD + (size_t)rem * 8;
  unsigned short* lo = hi + DD * DD;
#pragma unroll
  for (int i = 0; i < 8; ++i) {
    float w = W[(size_t)(k0 + i) * DD + col];
    unsigned short h = f2bf(w);
    hi[i] = h;
    lo[i] = f2bf(w - bf2f(h));
  }
}

// ---------------- fp16 mirror init ----------------
__global__ __launch_bounds__(256) void xh_init_k(const float* __restrict__ X,
                                                 _Float16* __restrict__ Xh) {
  int t = blockIdx.x * 256 + threadIdx.x;
  if (t >= NN * DD / 8) return;
  const float4* p = (const float4*)X + (size_t)t * 2;
  float4 a = p[0], b = p[1];
  half8 h;
  h[0] = (_Float16)a.x; h[1] = (_Float16)a.y; h[2] = (_Float16)a.z; h[3] = (_Float16)a.w;
  h[4] = (_Float16)b.x; h[5] = (_Float16)b.y; h[6] = (_Float16)b.z; h[7] = (_Float16)b.w;
  *(half8*)(Xh + (size_t)t * 8) = h;
}

// ---------------- fused layer: aggregate -> GEMM1+ReLU -> GEMM2+resid ----------------
// 256 threads = 4 waves = 2 wave-pairs; each pair owns one 16-row tile:
//   ztile: 16x132 fp32 (Z then H), rtile: 16x130 fp32 (residual stash).
// Streams (ELL idx, self fp32 row, outputs) use nontemporal; gather rows cached.
template<int WRITE_H>
__global__ __launch_bounds__(256) void fused_layer_k(
    const float* __restrict__ Xf_in, const _Float16* __restrict__ Xh_in,
    const int* __restrict__ cnt, const int* __restrict__ ell,
    const float* __restrict__ eps, int layer,
    const unsigned short* __restrict__ Wp1, const float* __restrict__ b1,
    const unsigned short* __restrict__ Wp2, const float* __restrict__ b2,
    float* __restrict__ Xf_out, _Float16* __restrict__ Xh_out)
{
  __shared__ float ztile[2][16 * 132];
  __shared__ float rtile[2][16 * 130];
  const int w = threadIdx.x >> 6, l = threadIdx.x & 63;
  const int pair = w >> 1, h = w & 1;
  const int mt = blockIdx.x * 2 + pair;
  const bool active = (mt < MT_TOTAL);
  const int c = l & 15, grp = l >> 4;
  float* my = ztile[pair];
  float* rz = rtile[pair];

  // ---- phase A: aggregation (8 rows per wave) ----
  if (active) {
    const float e1 = 1.0f + eps[layer];
#pragma unroll
    for (int pass = 0; pass < 2; ++pass) {
      int nl = h * 8 + pass * 4 + grp;
      int node = mt * 16 + nl;
      int deg = cnt[node]; deg = deg > ELLW ? ELLW : deg;
      const int* el = ell + (size_t)node * ELLW;
      const i32x4* el4 = (const i32x4*)el;
      float acc[8];
      float selfv[8];
      {
        const f32x4v* xr = (const f32x4v*)(Xf_in + (size_t)node * DD + c * 8);
        f32x4v a0 = __builtin_nontemporal_load(xr);
        f32x4v a1 = __builtin_nontemporal_load(xr + 1);
#pragma unroll
        for (int i = 0; i < 4; ++i) { selfv[i] = a0[i]; selfv[4 + i] = a1[i]; }
#pragma unroll
        for (int i = 0; i < 8; ++i) acc[i] = e1 * selfv[i];
      }
      // stash residual row into LDS
      {
        float* rd = rz + nl * 130 + c * 8;
#pragma unroll
        for (int i = 0; i < 8; ++i) rd[i] = selfv[i];
      }
      int nf = deg >> 2;
      i32x4 nxt;
      if (nf) nxt = __builtin_nontemporal_load(el4);
      for (int t = 0; t < nf; ++t) {
        i32x4 cur = nxt;
        if (t + 1 < nf) nxt = __builtin_nontemporal_load(el4 + t + 1);
        half8 v0 = *(const half8*)(Xh_in + (size_t)cur[0] * DD + c * 8);
        half8 v1 = *(const half8*)(Xh_in + (size_t)cur[1] * DD + c * 8);
        half8 v2 = *(const half8*)(Xh_in + (size_t)cur[2] * DD + c * 8);
        half8 v3 = *(const half8*)(Xh_in + (size_t)cur[3] * DD + c * 8);
#pragma unroll
        for (int i = 0; i < 8; ++i)
          acc[i] += ((float)v0[i] + (float)v1[i]) + ((float)v2[i] + (float)v3[i]);
      }
      for (int j = nf * 4; j < deg; ++j) {
        int s = __builtin_nontemporal_load(el + j);
        half8 v = *(const half8*)(Xh_in + (size_t)s * DD + c * 8);
#pragma unroll
        for (int i = 0; i < 8; ++i) acc[i] += (float)v[i];
      }
      float* dst = my + nl * 132 + c * 8;
      *(float4*)dst = make_float4(acc[0], acc[1], acc[2], acc[3]);
      *(float4*)(dst + 4) = make_float4(acc[4], acc[5], acc[6], acc[7]);
    }
  }
  __syncthreads();

  // ---- phase B: GEMM1 (Z @ W1) on nt half, ReLU, H -> LDS ----
  f32x4 acc1[4];
#pragma unroll
  for (int nt = 0; nt < 4; ++nt) acc1[nt] = (f32x4){0.f, 0.f, 0.f, 0.f};
  if (active) {
    const float* arow = my + (l & 15) * 132;
    const unsigned short* Whi = Wp1;
    const unsigned short* Wlo = Wp1 + DD * DD;
#pragma unroll
    for (int ks = 0; ks < 4; ++ks) {
      const float* zp = arow + ks * 32 + grp * 8;
      float4 z0 = *(const float4*)zp, z1 = *(const float4*)(zp + 4);
      bf16x8 ahi, alo; cvt8(z0, z1, &ahi, &alo);
#pragma unroll
      for (int nt = 0; nt < 4; ++nt) {
        int ntb = h * 4 + nt;
        size_t off = ((size_t)(ntb * 4 + ks) * 64 + l) * 8;
        bf16x8 bhi = *(const bf16x8*)(Whi + off);
        bf16x8 blo = *(const bf16x8*)(Wlo + off);
        acc1[nt] = __builtin_amdgcn_mfma_f32_16x16x32_bf16(ahi, bhi, acc1[nt], 0, 0, 0);
        acc1[nt] = __builtin_amdgcn_mfma_f32_16x16x32_bf16(ahi, blo, acc1[nt], 0, 0, 0);
        acc1[nt] = __builtin_amdgcn_mfma_f32_16x16x32_bf16(alo, bhi, acc1[nt], 0, 0, 0);
      }
    }
  }
  __syncthreads();   // all Z reads complete before H overwrites the tile

  if (active) {
#pragma unroll
    for (int nt = 0; nt < 4; ++nt) {
      int ntb = h * 4 + nt;
      float bv = b1[ntb * 16 + c];
#pragma unroll
      for (int r = 0; r < 4; ++r)
        my[(grp * 4 + r) * 132 + ntb * 16 + c] = fmaxf(acc1[nt][r] + bv, 0.f);
    }
  }
  __syncthreads();

  // ---- phase C: GEMM2 (H @ W2) on nt half + bias + residual(LDS), NT-write out ----
  f32x4 acc2[4];
#pragma unroll
  for (int nt = 0; nt < 4; ++nt) acc2[nt] = (f32x4){0.f, 0.f, 0.f, 0.f};
  if (active) {
    const float* arow = my + (l & 15) * 132;
    const unsigned short* Whi = Wp2;
    const unsigned short* Wlo = Wp2 + DD * DD;
#pragma unroll
    for (int ks = 0; ks < 4; ++ks) {
      const float* hp = arow + ks * 32 + grp * 8;
      float4 h0 = *(const float4*)hp, h1 = *(const float4*)(hp + 4);
      bf16x8 ahi, alo; cvt8(h0, h1, &ahi, &alo);
#pragma unroll
      for (int nt = 0; nt < 4; ++nt) {
        int ntb = h * 4 + nt;
        size_t off = ((size_t)(ntb * 4 + ks) * 64 + l) * 8;
        bf16x8 bhi = *(const bf16x8*)(Whi + off);
        bf16x8 blo = *(const bf16x8*)(Wlo + off);
        acc2[nt] = __builtin_amdgcn_mfma_f32_16x16x32_bf16(ahi, bhi, acc2[nt], 0, 0, 0);
        acc2[nt] = __builtin_amdgcn_mfma_f32_16x16x32_bf16(ahi, blo, acc2[nt], 0, 0, 0);
        acc2[nt] = __builtin_amdgcn_mfma_f32_16x16x32_bf16(alo, bhi, acc2[nt], 0, 0, 0);
      }
    }
#pragma unroll
    for (int nt = 0; nt < 4; ++nt) {
      int ntb = h * 4 + nt;
      int col = ntb * 16 + c;
      float bv = b2[col];
#pragma unroll
      for (int r = 0; r < 4; ++r) {
        int row = grp * 4 + r;
        int node = mt * 16 + row;
        size_t idx = (size_t)node * DD + col;
        float v = acc2[nt][r] + bv + rz[row * 130 + col];
        __builtin_nontemporal_store(v, Xf_out + idx);
        if (WRITE_H) __builtin_nontemporal_store((_Float16)v, Xh_out + idx);
      }
    }
  }
}

extern "C" void kernel_launch(void* const* d_in, const int* in_sizes, int n_in,
                              void* d_out, int out_size, void* d_ws, size_t ws_size,
                              hipStream_t stream) {
  const float* X   = (const float*)d_in[0];
  const int*   ei  = (const int*)d_in[1];
  const float* eps = (const float*)d_in[2];
  const float* W1  = (const float*)d_in[3];
  const float* b1  = (const float*)d_in[4];
  const float* W2  = (const float*)d_in[5];
  const float* b2  = (const float*)d_in[6];
  float* Xout = (float*)d_out;

  char* ws = (char*)d_ws;
  size_t off = 0;
  int* cnt = (int*)(ws + off); off += 256 * (((size_t)NN * 4 + 255) / 256);
  int* ell = (int*)(ws + off); off += (size_t)NN * ELLW * 4;
  unsigned short* Wp = (unsigned short*)(ws + off); off += (size_t)6 * 2 * DD * DD * 2;
  _Float16* Xh0 = (_Float16*)(ws + off); off += (size_t)NN * DD * 2;
  _Float16* Xh1 = (_Float16*)(ws + off); off += (size_t)NN * DD * 2;

  hipMemsetAsync(cnt, 0, NN * 4, stream);
  build_ell_k<<<(NE + 255) / 256, 256, 0, stream>>>(ei, cnt, ell);
  pack_w_k<<<(6 * 2048 + 255) / 256, 256, 0, stream>>>(W1, W2, Wp);
  xh_init_k<<<(NN * DD / 8 + 255) / 256, 256, 0, stream>>>(X, Xh0);

  const int fgrid = (MT_TOTAL + 1) / 2;  // 1563 blocks x 4 waves (2 tiles/block)
  fused_layer_k<1><<<fgrid, 256, 0, stream>>>(X, Xh0, cnt, ell, eps, 0,
      Wp + (size_t)0 * 2 * DD * DD, b1 + 0 * DD,
      Wp + (size_t)3 * 2 * DD * DD, b2 + 0 * DD, Xout, Xh1);
  fused_layer_k<1><<<fgrid, 256, 0, stream>>>(Xout, Xh1, cnt, ell, eps, 1,
      Wp + (size_t)1 * 2 * DD * DD, b1 + 1 * DD,
      Wp + (size_t)4 * 2 * DD * DD, b2 + 1 * DD, Xout, Xh0);
  fused_layer_k<0><<<fgrid, 256, 0, stream>>>(Xout, Xh0, cnt, ell, eps, 2,
      Wp + (size_t)2 * 2 * DD * DD, b1 + 2 * DD,
      Wp + (size_t)5 * 2 * DD * DD, b2 + 2 * DD, Xout, nullptr);
}

// Round 7
// 212.859 us; speedup vs baseline: 1.1128x; 1.1128x over previous
//
#include <hip/hip_runtime.h>

#define NN 50000
#define NE 800000
#define DD 128
#define NL 3
#define ELLW 64
#define MT_TOTAL (NN / 16)                     // 3125 tiles of 16 rows
#define EDGE_BLKS ((NE + 255) / 256)           // 3125
#define PACK_BLKS ((6 * 2048 * 8 + 2047) / 2048) // 48 (12288 threads / 256)
#define INIT_BLKS ((NN * DD / 8 + 255) / 256)  // 3125

typedef short bf16x8 __attribute__((ext_vector_type(8)));
typedef float f32x4 __attribute__((ext_vector_type(4)));
typedef _Float16 half8 __attribute__((ext_vector_type(8)));
typedef unsigned short u16x8 __attribute__((ext_vector_type(8)));

__device__ __forceinline__ unsigned short f2bf(float x) {
  unsigned u = __float_as_uint(x);
  u += 0x7FFFu + ((u >> 16) & 1u);          // RTN-even
  return (unsigned short)(u >> 16);
}
__device__ __forceinline__ float bf2f(unsigned short h) {
  return __uint_as_float(((unsigned)h) << 16);
}
__device__ __forceinline__ void cvt8(const float* zz, bf16x8* hi, bf16x8* lo) {
#pragma unroll
  for (int i = 0; i < 8; ++i) {
    unsigned short h = f2bf(zz[i]);
    (*hi)[i] = (short)h;
    (*lo)[i] = (short)f2bf(zz[i] - bf2f(h));
  }
}

// ---------------- fused prologue: ELL build + W pack + fp16 mirror ----------------
__global__ __launch_bounds__(256) void prologue_k(
    const int* __restrict__ ei, int* __restrict__ cnt, unsigned short* __restrict__ ell,
    const float* __restrict__ W1, const float* __restrict__ W2,
    unsigned short* __restrict__ Wp,
    const float* __restrict__ X, _Float16* __restrict__ Xh)
{
  int b = blockIdx.x;
  if (b < EDGE_BLKS) {
    int e = b * 256 + threadIdx.x;
    if (e < NE) {
      int s = ei[e];        // src
      int d = ei[NE + e];   // dst
      int pos = atomicAdd(&cnt[d], 1);
      if (pos < ELLW) ell[(size_t)d * ELLW + pos] = (unsigned short)s;
    }
  } else if (b < EDGE_BLKS + PACK_BLKS) {
    int t = (b - EDGE_BLKS) * 256 + threadIdx.x;
    if (t < 6 * 2048) {
      int m = t >> 11;
      int rem = t & 2047;              // (nt*4+ks)*64 + lane
      int l = rem & 63;
      int ntks = rem >> 6;
      int ks = ntks & 3, nt = ntks >> 2;
      const float* W = (m < 3) ? (W1 + (size_t)m * DD * DD) : (W2 + (size_t)(m - 3) * DD * DD);
      int col = nt * 16 + (l & 15);
      int k0 = ks * 32 + (l >> 4) * 8;
      unsigned short* hi = Wp + (size_t)m * 2 * DD * DD + (size_t)rem * 8;
      unsigned short* lo = hi + DD * DD;
#pragma unroll
      for (int i = 0; i < 8; ++i) {
        float w = W[(size_t)(k0 + i) * DD + col];
        unsigned short h = f2bf(w);
        hi[i] = h;
        lo[i] = f2bf(w - bf2f(h));
      }
    }
  } else {
    int t = (b - EDGE_BLKS - PACK_BLKS) * 256 + threadIdx.x;
    if (t < NN * DD / 8) {
      const float4* p = (const float4*)X + (size_t)t * 2;
      float4 a = p[0], bb = p[1];
      half8 h;
      h[0] = (_Float16)a.x;  h[1] = (_Float16)a.y;  h[2] = (_Float16)a.z;  h[3] = (_Float16)a.w;
      h[4] = (_Float16)bb.x; h[5] = (_Float16)bb.y; h[6] = (_Float16)bb.z; h[7] = (_Float16)bb.w;
      *(half8*)(Xh + (size_t)t * 8) = h;
    }
  }
}

// ---------------- fused layer: aggregate -> GEMM1+ReLU -> GEMM2+resid ----------------
// State between layers is fp16 only. 256 threads = 2 wave-pairs, one 16-row tile each.
// ztile: 16x132 fp32 (Z then H). rtile: 16x136 fp16 (residual stash).
// SELF_F32: layer 0 reads self/resid from fp32 input X. OUT_F32: final layer -> d_out.
template<int SELF_F32, int OUT_F32>
__global__ __launch_bounds__(256) void fused_layer_k(
    const float* __restrict__ Xf_in, const _Float16* __restrict__ Xh_in,
    const int* __restrict__ cnt, const unsigned short* __restrict__ ell,
    const float* __restrict__ eps, int layer,
    const unsigned short* __restrict__ Wp1, const float* __restrict__ b1,
    const unsigned short* __restrict__ Wp2, const float* __restrict__ b2,
    float* __restrict__ Xf_out, _Float16* __restrict__ Xh_out)
{
  __shared__ float ztile[2][16 * 132];
  __shared__ unsigned short rtile[2][16 * 136];
  const int w = threadIdx.x >> 6, l = threadIdx.x & 63;
  const int pair = w >> 1, h = w & 1;
  const int mt = blockIdx.x * 2 + pair;
  const bool active = (mt < MT_TOTAL);
  const int c = l & 15, grp = l >> 4;
  float* my = ztile[pair];
  unsigned short* rz = rtile[pair];

  // ---- phase A: aggregation (8 rows per wave, 2 passes x 4 nodes x 16 lanes) ----
  if (active) {
    const float e1 = 1.0f + eps[layer];
#pragma unroll
    for (int pass = 0; pass < 2; ++pass) {
      int nl = h * 8 + pass * 4 + grp;
      int node = mt * 16 + nl;
      int deg = cnt[node]; deg = deg > ELLW ? ELLW : deg;
      const unsigned short* el = ell + (size_t)node * ELLW;
      float acc[8];
      // self term + residual stash (fp16 bits)
      if (SELF_F32) {
        const float* xr = Xf_in + (size_t)node * DD + c * 8;
        float4 a0 = *(const float4*)xr, a1 = *(const float4*)(xr + 4);
        float sv[8] = {a0.x, a0.y, a0.z, a0.w, a1.x, a1.y, a1.z, a1.w};
        u16x8 rb;
#pragma unroll
        for (int i = 0; i < 8; ++i) {
          acc[i] = e1 * sv[i];
          _Float16 hh = (_Float16)sv[i];
          rb[i] = *(unsigned short*)&hh;
        }
        *(u16x8*)(rz + nl * 136 + c * 8) = rb;
      } else {
        half8 sv = *(const half8*)(Xh_in + (size_t)node * DD + c * 8);
#pragma unroll
        for (int i = 0; i < 8; ++i) acc[i] = e1 * (float)sv[i];
        *(u16x8*)(rz + nl * 136 + c * 8) = *(const u16x8*)&sv;
      }
      // neighbor gather: 8 independent rows per index batch
      int nf8 = deg >> 3;
      const u16x8* el8 = (const u16x8*)el;
      u16x8 nxt;
      if (nf8) nxt = el8[0];
      for (int t = 0; t < nf8; ++t) {
        u16x8 cur = nxt;
        if (t + 1 < nf8) nxt = el8[t + 1];
        half8 v0 = *(const half8*)(Xh_in + (size_t)cur[0] * DD + c * 8);
        half8 v1 = *(const half8*)(Xh_in + (size_t)cur[1] * DD + c * 8);
        half8 v2 = *(const half8*)(Xh_in + (size_t)cur[2] * DD + c * 8);
        half8 v3 = *(const half8*)(Xh_in + (size_t)cur[3] * DD + c * 8);
        half8 v4 = *(const half8*)(Xh_in + (size_t)cur[4] * DD + c * 8);
        half8 v5 = *(const half8*)(Xh_in + (size_t)cur[5] * DD + c * 8);
        half8 v6 = *(const half8*)(Xh_in + (size_t)cur[6] * DD + c * 8);
        half8 v7 = *(const half8*)(Xh_in + (size_t)cur[7] * DD + c * 8);
#pragma unroll
        for (int i = 0; i < 8; ++i)
          acc[i] += (((float)v0[i] + (float)v1[i]) + ((float)v2[i] + (float)v3[i]))
                  + (((float)v4[i] + (float)v5[i]) + ((float)v6[i] + (float)v7[i]));
      }
      for (int j = nf8 * 8; j < deg; ++j) {
        half8 v = *(const half8*)(Xh_in + (size_t)el[j] * DD + c * 8);
#pragma unroll
        for (int i = 0; i < 8; ++i) acc[i] += (float)v[i];
      }
      float* dst = my + nl * 132 + c * 8;
      *(float4*)dst = make_float4(acc[0], acc[1], acc[2], acc[3]);
      *(float4*)(dst + 4) = make_float4(acc[4], acc[5], acc[6], acc[7]);
    }
  }
  __syncthreads();

  // ---- phase B: GEMM1 (Z @ W1) on this wave's column half, ReLU, H -> LDS ----
  f32x4 acc1[4];
#pragma unroll
  for (int nt = 0; nt < 4; ++nt) acc1[nt] = (f32x4){0.f, 0.f, 0.f, 0.f};
  if (active) {
    const float* arow = my + (l & 15) * 132;
    const unsigned short* Whi = Wp1;
    const unsigned short* Wlo = Wp1 + DD * DD;
#pragma unroll
    for (int ks = 0; ks < 4; ++ks) {
      const float* zp = arow + ks * 32 + grp * 8;
      float zz[8] = {zp[0], zp[1], zp[2], zp[3], zp[4], zp[5], zp[6], zp[7]};
      bf16x8 ahi, alo; cvt8(zz, &ahi, &alo);
#pragma unroll
      for (int nt = 0; nt < 4; ++nt) {
        int ntb = h * 4 + nt;
        size_t off = ((size_t)(ntb * 4 + ks) * 64 + l) * 8;
        bf16x8 bhi = *(const bf16x8*)(Whi + off);
        bf16x8 blo = *(const bf16x8*)(Wlo + off);
        acc1[nt] = __builtin_amdgcn_mfma_f32_16x16x32_bf16(ahi, bhi, acc1[nt], 0, 0, 0);
        acc1[nt] = __builtin_amdgcn_mfma_f32_16x16x32_bf16(ahi, blo, acc1[nt], 0, 0, 0);
        acc1[nt] = __builtin_amdgcn_mfma_f32_16x16x32_bf16(alo, bhi, acc1[nt], 0, 0, 0);
      }
    }
  }
  __syncthreads();   // all Z reads complete before H overwrites the tile

  if (active) {
#pragma unroll
    for (int nt = 0; nt < 4; ++nt) {
      int ntb = h * 4 + nt;
      float bv = b1[ntb * 16 + c];
#pragma unroll
      for (int r = 0; r < 4; ++r)
        my[(grp * 4 + r) * 132 + ntb * 16 + c] = fmaxf(acc1[nt][r] + bv, 0.f);
    }
  }
  __syncthreads();

  // ---- phase C: GEMM2 (H @ W2) + bias + residual(LDS fp16), write state/output ----
  f32x4 acc2[4];
#pragma unroll
  for (int nt = 0; nt < 4; ++nt) acc2[nt] = (f32x4){0.f, 0.f, 0.f, 0.f};
  if (active) {
    const float* arow = my + (l & 15) * 132;
    const unsigned short* Whi = Wp2;
    const unsigned short* Wlo = Wp2 + DD * DD;
#pragma unroll
    for (int ks = 0; ks < 4; ++ks) {
      const float* hp = arow + ks * 32 + grp * 8;
      float hh[8] = {hp[0], hp[1], hp[2], hp[3], hp[4], hp[5], hp[6], hp[7]};
      bf16x8 ahi, alo; cvt8(hh, &ahi, &alo);
#pragma unroll
      for (int nt = 0; nt < 4; ++nt) {
        int ntb = h * 4 + nt;
        size_t off = ((size_t)(ntb * 4 + ks) * 64 + l) * 8;
        bf16x8 bhi = *(const bf16x8*)(Whi + off);
        bf16x8 blo = *(const bf16x8*)(Wlo + off);
        acc2[nt] = __builtin_amdgcn_mfma_f32_16x16x32_bf16(ahi, bhi, acc2[nt], 0, 0, 0);
        acc2[nt] = __builtin_amdgcn_mfma_f32_16x16x32_bf16(ahi, blo, acc2[nt], 0, 0, 0);
        acc2[nt] = __builtin_amdgcn_mfma_f32_16x16x32_bf16(alo, bhi, acc2[nt], 0, 0, 0);
      }
    }
#pragma unroll
    for (int nt = 0; nt < 4; ++nt) {
      int ntb = h * 4 + nt;
      int col = ntb * 16 + c;
      float bv = b2[col];
#pragma unroll
      for (int r = 0; r < 4; ++r) {
        int row = grp * 4 + r;
        int node = mt * 16 + row;
        size_t idx = (size_t)node * DD + col;
        unsigned short rb = rz[row * 136 + col];
        float rv = (float)(*(_Float16*)&rb);
        float v = acc2[nt][r] + bv + rv;
        if (OUT_F32) Xf_out[idx] = v;
        else         Xh_out[idx] = (_Float16)v;
      }
    }
  }
}

extern "C" void kernel_launch(void* const* d_in, const int* in_sizes, int n_in,
                              void* d_out, int out_size, void* d_ws, size_t ws_size,
                              hipStream_t stream) {
  const float* X   = (const float*)d_in[0];
  const int*   ei  = (const int*)d_in[1];
  const float* eps = (const float*)d_in[2];
  const float* W1  = (const float*)d_in[3];
  const float* b1  = (const float*)d_in[4];
  const float* W2  = (const float*)d_in[5];
  const float* b2  = (const float*)d_in[6];
  float* Xout = (float*)d_out;

  char* ws = (char*)d_ws;
  size_t off = 0;
  int* cnt = (int*)(ws + off); off += 256 * (((size_t)NN * 4 + 255) / 256);
  unsigned short* ell = (unsigned short*)(ws + off); off += (size_t)NN * ELLW * 2;
  unsigned short* Wp = (unsigned short*)(ws + off); off += (size_t)6 * 2 * DD * DD * 2;
  off = 256 * ((off + 255) / 256);
  _Float16* Xh0 = (_Float16*)(ws + off); off += (size_t)NN * DD * 2;
  _Float16* Xh1 = (_Float16*)(ws + off); off += (size_t)NN * DD * 2;

  hipMemsetAsync(cnt, 0, NN * 4, stream);
  prologue_k<<<EDGE_BLKS + PACK_BLKS + INIT_BLKS, 256, 0, stream>>>(
      ei, cnt, ell, W1, W2, Wp, X, Xh0);

  const int fgrid = (MT_TOTAL + 1) / 2;  // 1563 blocks x 4 waves (2 tiles/block)
  // layer 0: self/resid from fp32 input X, gather Xh0, state out -> Xh1 (fp16)
  fused_layer_k<1, 0><<<fgrid, 256, 0, stream>>>(X, Xh0, cnt, ell, eps, 0,
      Wp + (size_t)0 * 2 * DD * DD, b1 + 0 * DD,
      Wp + (size_t)3 * 2 * DD * DD, b2 + 0 * DD, nullptr, Xh1);
  // layer 1: fp16 state Xh1 -> Xh0
  fused_layer_k<0, 0><<<fgrid, 256, 0, stream>>>(nullptr, Xh1, cnt, ell, eps, 1,
      Wp + (size_t)1 * 2 * DD * DD, b1 + 1 * DD,
      Wp + (size_t)4 * 2 * DD * DD, b2 + 1 * DD, nullptr, Xh0);
  // layer 2: fp16 state Xh0 -> fp32 d_out
  fused_layer_k<0, 1><<<fgrid, 256, 0, stream>>>(nullptr, Xh0, cnt, ell, eps, 2,
      Wp + (size_t)2 * 2 * DD * DD, b1 + 2 * DD,
      Wp + (size_t)5 * 2 * DD * DD, b2 + 2 * DD, Xout, nullptr);
}